// Round 5
// baseline (123.635 us; speedup 1.0000x reference)
//
#include <hip/hip_runtime.h>
#include <math.h>

#define BB   4
#define MM   1024
#define NN   1024
#define DD   9
#define KSEL 16
#define NROW (BB * MM)        // 4096 rows; wave r handles intra-row r AND outer-row r

// Workspace. yT first => 16B-aligned float4 planes. Every field written before
// read each launch. Harness re-poisons the full d_ws (2 x ~39.3us fills)
// inside the timed window: ~79us session floor we cannot touch.
// R1: __launch_bounds__(256,4) -> VGPR=64 -> 16.7MB scratch spill (46us dist).
// R2: ticket finalize (1024 serialized acq_rel atomics) + 2x inlined
//     selection networks -> 41us dist at 16% occupancy.
// R3: dist fixed but ONE-block setup = ~19us serial tail on a single CU.
// R4: 8-block redundant prep: own-portion 29->19.8us (prep still ~8us:
//     cold loads issued late + 1-wave GJ on the critical path).
// R5: (a) finalize launch removed: per-block LDS reduce + 3 native fp32
//     atomics (unsafeAtomicAdd -> global_atomic_add_f32, NO CAS) into out,
//     zeroed by prep; (b) prep issues ALL global loads at kernel entry so
//     HBM latency hides under phases 1-2.
struct Ws {
  float yT[BB * DD * NN];     // [b][p][j] SoA planes
  float qy[BB * NN];          // y_j^T Cinv y_j
  float cnt;
  float mean[DD];
  float cinv[DD * DD];
};

// ---------------------------------------------------------------------------
// Kernel A: 8 blocks x 512. All global loads issued at entry (T14 split:
// issue-early, use-late; compiler waits with partial vmcnt at first use).
// Phase 1: EVERY block computes the full masked moment partials (8
// consecutive rows/thread). Phase 2: wave 0 fp64 Gauss-Jordan (cov of ~2048
// N(0,1) samples is SPD, diag~1 => no pivoting, pinv == inverse); all blocks
// derive identical Cs; block 0 publishes + zeroes out[0..2] for dist's
// atomics (kernel-boundary ordering). Phase 3: qy + SoA transpose, ONE
// output per thread (coalesced plane stores).
// ---------------------------------------------------------------------------
__global__ __launch_bounds__(512) void prep_kernel(
    const float* __restrict__ outputs, const float* __restrict__ targets,
    const int* __restrict__ mask, Ws* __restrict__ ws,
    float* __restrict__ out) {
  const int tid = threadIdx.x;  // 0..511
  __shared__ float part[8][55];
  __shared__ double Sd[55];
  __shared__ float Cs[DD * DD];

  // ---- issue ALL global loads up front (targets 18xf4, mask 2xi4, y 9xf32)
  float4 st4[18];
  {
    const float4* tp = (const float4*)targets + 18 * tid;
#pragma unroll
    for (int i = 0; i < 18; ++i) st4[i] = tp[i];
  }
  const int4 m0 = ((const int4*)mask)[2 * tid];
  const int4 m1 = ((const int4*)mask)[2 * tid + 1];
  const int j3 = (blockIdx.x << 9) + tid;  // phase-3 output index 0..4095
  float y[DD];
#pragma unroll
  for (int k = 0; k < DD; ++k) y[k] = outputs[j3 * DD + k];

  // ---- phase 1: moments over rows 8t..8t+7 (72 floats = 18 float4, exact)
  float acc[55];
#pragma unroll
  for (int k = 0; k < 55; ++k) acc[k] = 0.f;
  {
    const float* f = (const float*)st4;
    const int mk[8] = {m0.x, m0.y, m0.z, m0.w, m1.x, m1.y, m1.z, m1.w};
#pragma unroll
    for (int rr = 0; rr < 8; ++rr) {
      if (mk[rr] != 0) {
        const float* t = f + rr * DD;
        acc[0] += 1.f;
#pragma unroll
        for (int k = 0; k < DD; ++k) acc[1 + k] += t[k];
        int u = 10;
#pragma unroll
        for (int p = 0; p < DD; ++p)
#pragma unroll
          for (int q = p; q < DD; ++q) acc[u++] += t[p] * t[q];
      }
    }
  }
#pragma unroll
  for (int k = 0; k < 55; ++k) {
    float v = acc[k];
#pragma unroll
    for (int off = 32; off > 0; off >>= 1) v += __shfl_down(v, off, 64);
    if ((tid & 63) == 0) part[tid >> 6][k] = v;
  }
  if (blockIdx.x == 0 && tid == 0) {  // zero the atomic accumulators
    out[0] = 0.f;
    out[1] = 0.f;
    out[2] = 0.f;
  }
  __syncthreads();

  if (tid < 55) {
    double s = 0.0;
#pragma unroll
    for (int w = 0; w < 8; ++w) s += (double)part[w][tid];
    Sd[tid] = s;
  }
  __syncthreads();

  // ---- phase 2: fp64 Gauss-Jordan on wave 0 (lane p owns augmented row p)
  if (tid < 64) {
    const int lane = tid;
    const double cnt = Sd[0];
    const int p = (lane < DD) ? lane : 0;  // junk lanes mirror row 0
    double row[2 * DD];
    {
      const double mu_p = Sd[1 + p] / cnt;
#pragma unroll
      for (int q = 0; q < DD; ++q) {
        const int pp = (p < q) ? p : q;
        const int qq = (p < q) ? q : p;
        const int idx = 10 + 9 * pp - (pp * (pp - 1)) / 2 + (qq - pp);
        row[q] = (Sd[idx] - cnt * mu_p * (Sd[1 + q] / cnt)) / (cnt - 1.0);
        row[DD + q] = (p == q) ? 1.0 : 0.0;
      }
    }
#pragma unroll
    for (int c = 0; c < DD; ++c) {
      const double diag = __shfl(row[c], c, 64);
      const double dinv = 1.0 / diag;
      if (lane == c) {
#pragma unroll
        for (int q = 0; q < 2 * DD; ++q) row[q] *= dinv;
      }
      const double f = (lane == c) ? 0.0 : row[c];
#pragma unroll
      for (int q = 0; q < 2 * DD; ++q) {
        const double pv = __shfl(row[q], c, 64);
        row[q] -= f * pv;
      }
    }
    if (lane < DD) {
#pragma unroll
      for (int q = 0; q < DD; ++q) {
        const float cf = (float)row[DD + q];
        Cs[lane * DD + q] = cf;
        if (blockIdx.x == 0) ws->cinv[lane * DD + q] = cf;
      }
    }
    if (lane == 0 && blockIdx.x == 0) {
      ws->cnt = (float)cnt;
#pragma unroll
      for (int q = 0; q < DD; ++q) ws->mean[q] = (float)(Sd[1 + q] / cnt);
    }
  }
  __syncthreads();

  // ---- phase 3: qy + SoA transpose, ONE output per thread (coalesced)
  {
    const int b = j3 >> 10;
    const int jj = j3 & (NN - 1);
    float C[DD * DD];
#pragma unroll
    for (int k = 0; k < DD * DD; ++k) C[k] = Cs[k];
    float q = 0.f;
#pragma unroll
    for (int p = 0; p < DD; ++p) {
      float s = 0.f;
#pragma unroll
      for (int t = 0; t < DD; ++t) s += C[p * DD + t] * y[t];
      q += y[p] * s;
      ws->yT[(b * DD + p) * NN + jj] = y[p];
    }
    ws->qy[j3] = q;
  }
}

// ---------------------------------------------------------------------------
// Kernel B: 1024 blocks x 256, uncapped VGPRs (R1 lesson). One wave per row r
// handles BOTH the intra row (if unmasked) and the outer row: a single pass
// over the yT/qy planes feeds both accumulator sets. The top-16 selection
// network exists ONCE, in a no-unroll loop over sides (R2 lesson). Dead
// waves run only s=1 (outer). Epilogue: per-block LDS reduce of the 4 wave
// partials, then 3 native fp32 atomics (unsafeAtomicAdd ->
// global_atomic_add_f32) of the pre-scaled partials into out. No finalize
// kernel, no ticket. 4096*16 == 2^16 => exact power-of-two outer scale.
// ---------------------------------------------------------------------------
__global__ __launch_bounds__(256) void dist_kernel(
    const float* __restrict__ outputs, const float* __restrict__ targets,
    const int* __restrict__ mask, Ws* __restrict__ ws,
    float* __restrict__ out) {
  const int tid = threadIdx.x;
  const int wv = tid >> 6;
  const int lane = tid & 63;
  const int r = blockIdx.x * 4 + wv;  // 0..4095
  const int b = r >> 10;
  const bool live = (mask[r] != 0);   // wave-uniform

  // outer side: u = y_r + mean (reference subtracts mean from the DIFF);
  // intra side: a = t_r - mean. Both computed unconditionally - one
  // straight-line code path.
  float wo[DD], wi[DD];
  float qa_o = 0.f, qa_i = 0.f;
  {
    float ao[DD], ai[DD];
#pragma unroll
    for (int k = 0; k < DD; ++k) {
      const float mk = ws->mean[k];
      ao[k] = outputs[r * DD + k] + mk;
      ai[k] = targets[r * DD + k] - mk;
    }
#pragma unroll
    for (int p = 0; p < DD; ++p) {
      float so = 0.f, si = 0.f;
#pragma unroll
      for (int t = 0; t < DD; ++t) {
        const float cv = ws->cinv[p * DD + t];
        so += cv * ao[t];
        si += cv * ai[t];
      }
      wo[p] = so;
      qa_o += ao[p] * so;
      wi[p] = si;
      qa_i += ai[p] * si;
    }
  }

  float vi[16], vo[16];
#pragma unroll
  for (int k = 0; k < 16; ++k) {
    vi[k] = 0.f;
    vo[k] = 0.f;
  }
  const float* __restrict__ yTb = ws->yT + (size_t)b * DD * NN;
#pragma unroll
  for (int p = 0; p < DD; ++p) {
    const float4* __restrict__ pl = (const float4*)(yTb + (size_t)p * NN);
#pragma unroll
    for (int c = 0; c < 4; ++c) {
      const float4 y4 = pl[c * 64 + lane];
      vi[c * 4 + 0] += wi[p] * y4.x;
      vi[c * 4 + 1] += wi[p] * y4.y;
      vi[c * 4 + 2] += wi[p] * y4.z;
      vi[c * 4 + 3] += wi[p] * y4.w;
      vo[c * 4 + 0] += wo[p] * y4.x;
      vo[c * 4 + 1] += wo[p] * y4.y;
      vo[c * 4 + 2] += wo[p] * y4.z;
      vo[c * 4 + 3] += wo[p] * y4.w;
    }
  }
  {
    const float4* __restrict__ q4 = (const float4*)(ws->qy + (size_t)b * NN);
#pragma unroll
    for (int c = 0; c < 4; ++c) {
      const float4 qv = q4[c * 64 + lane];
      vi[c * 4 + 0] = qa_i + qv.x - 2.f * vi[c * 4 + 0];
      vi[c * 4 + 1] = qa_i + qv.y - 2.f * vi[c * 4 + 1];
      vi[c * 4 + 2] = qa_i + qv.z - 2.f * vi[c * 4 + 2];
      vi[c * 4 + 3] = qa_i + qv.w - 2.f * vi[c * 4 + 3];
      vo[c * 4 + 0] = qa_o + qv.x - 2.f * vo[c * 4 + 0];
      vo[c * 4 + 1] = qa_o + qv.y - 2.f * vo[c * 4 + 1];
      vo[c * 4 + 2] = qa_o + qv.z - 2.f * vo[c * 4 + 2];
      vo[c * 4 + 3] = qa_o + qv.w - 2.f * vo[c * 4 + 3];
    }
  }

  // ---- top-16 selection: ONE network instance, looped over sides.
  // Per-lane bitonic sort + 6 shfl_xor half-cleaner rounds; re-merge after
  // the last round skipped (half-cleaner output already holds the top-16
  // multiset). Dead waves (live==0) run only s=1 (outer).
  float si_sum = 0.f, so_sum = 0.f;
#pragma unroll 1
  for (int s = live ? 0 : 1; s < 2; ++s) {
    float v[16];
#pragma unroll
    for (int i = 0; i < 16; ++i) v[i] = (s == 0) ? vi[i] : vo[i];

#pragma unroll
    for (int k = 2; k <= 16; k <<= 1) {
#pragma unroll
      for (int j = k >> 1; j > 0; j >>= 1) {
#pragma unroll
        for (int i = 0; i < 16; ++i) {
          const int l = i ^ j;
          if (l > i) {
            const bool up = ((i & k) == 0);
            const float lo = fminf(v[i], v[l]);
            const float hi = fmaxf(v[i], v[l]);
            v[i] = up ? lo : hi;
            v[l] = up ? hi : lo;
          }
        }
      }
    }
#pragma unroll
    for (int off = 1; off < 64; off <<= 1) {
      float pr[16];
#pragma unroll
      for (int i = 0; i < 16; ++i) pr[i] = __shfl_xor(v[i], off, 64);
#pragma unroll
      for (int i = 0; i < 16; ++i) v[i] = fminf(v[i], pr[15 - i]);
      if (off < 32) {
#pragma unroll
        for (int j = 8; j > 0; j >>= 1) {
#pragma unroll
          for (int i = 0; i < 16; ++i) {
            const int l = i ^ j;
            if (l > i) {
              const float lo = fminf(v[i], v[l]);
              const float hi = fmaxf(v[i], v[l]);
              v[i] = lo;
              v[l] = hi;
            }
          }
        }
      }
    }
    float total = v[0];
#pragma unroll
    for (int k = 1; k < 16; ++k) total += v[k];
    if (s == 0) si_sum = total;
    else so_sum = total;
  }

  // ---- per-block reduce + native fp32 atomics into out (no 3rd kernel).
  // All waves reach here (no early returns above).
  __shared__ float bp_i[4], bp_o[4];
  if (lane == 0) {
    bp_i[wv] = si_sum;  // 0 for dead waves
    bp_o[wv] = so_sum;
  }
  __syncthreads();
  if (tid == 0) {
    const float sI = (bp_i[0] + bp_i[1] + bp_i[2] + bp_i[3]) / ws->cnt;
    const float sO =
        (bp_o[0] + bp_o[1] + bp_o[2] + bp_o[3]) * (1.0f / 65536.0f);
    unsafeAtomicAdd(&out[0], sI);
    unsafeAtomicAdd(&out[1], sI);
    unsafeAtomicAdd(&out[2], sO);
  }
}

extern "C" void kernel_launch(void* const* d_in, const int* in_sizes, int n_in,
                              void* d_out, int out_size, void* d_ws,
                              size_t ws_size, hipStream_t stream) {
  const float* outputs = (const float*)d_in[0];  // (4,1024,9) f32
  const float* targets = (const float*)d_in[1];  // (4,1024,9) f32
  const int* mask = (const int*)d_in[2];         // (4,1024) int32
  Ws* ws = (Ws*)d_ws;
  float* out = (float*)d_out;

  prep_kernel<<<8, 512, 0, stream>>>(outputs, targets, mask, ws, out);
  dist_kernel<<<NROW / 4, 256, 0, stream>>>(outputs, targets, mask, ws, out);
}

// Round 6
// 98.709 us; speedup vs baseline: 1.2525x; 1.2525x over previous
//
#include <hip/hip_runtime.h>
#include <math.h>

#define BB   4
#define MM   1024
#define NN   1024
#define DD   9
#define KSEL 16
#define NROW (BB * MM)        // 4096 row-slots per phase
#define NSLOT (2 * NROW)
#define NBLK (NSLOT / 4)      // 2048 blocks, 4 waves (row-slots) each

// Workspace. yT first => 16B-aligned float4 planes. Every field written
// before read (masked rows write rowsum=0) => no memset, no atomics.
// Harness re-poisons the full d_ws (2 x ~39.4us fills) in the timed window:
// ~79us session floor. Component ledger (measured R0-R5):
//   setup-1blk ~10us | prep8 ~3us | stats+prep ~5-6us(+gap)
//   dist-R0 (one side/wave) ~9.5us | dist-paired-sharedloop ~13us (worse!)
//   fin ~1.5us | same-line atomic tails: 30-45us (NEVER again: R2, R5)
// R6 = best component per slot: prep8 + dist-R0 + fin-R0.
struct Ws {
  float yT[BB * DD * NN];     // [b][p][j] SoA planes (4 KB each)
  float qy[BB * NN];          // y_j^T Cinv y_j
  float rowsum[NSLOT];        // [0,4096): intra; [4096,8192): outer
  float cnt;
  float mean[DD];
  float cinv[DD * DD];
};

// ---------------------------------------------------------------------------
// Kernel A: 8 blocks x 512 [R4-verified]. All global loads issued at entry
// (HBM latency hides under phases 1-2). Phase 1: EVERY block computes the
// full masked moment partials (8 consecutive rows/thread, float4-staged).
// Phase 2: wave 0 fp64 Gauss-Jordan (cov of ~2048 N(0,1) samples is SPD,
// diag~1 => no pivoting, pinv == inverse); all blocks derive identical Cs;
// block 0 publishes. Phase 3: qy + SoA transpose, ONE output per thread
// (coalesced plane stores). Redundant phases 1-2 cost ~1us/block on separate
// CUs - cheaper than a stats launch + gap + global partial round-trip.
// ---------------------------------------------------------------------------
__global__ __launch_bounds__(512) void prep_kernel(
    const float* __restrict__ outputs, const float* __restrict__ targets,
    const int* __restrict__ mask, Ws* __restrict__ ws) {
  const int tid = threadIdx.x;  // 0..511
  __shared__ float part[8][55];
  __shared__ double Sd[55];
  __shared__ float Cs[DD * DD];

  // ---- issue ALL global loads up front (targets 18xf4, mask 2xi4, y 9xf32)
  float4 st4[18];
  {
    const float4* tp = (const float4*)targets + 18 * tid;
#pragma unroll
    for (int i = 0; i < 18; ++i) st4[i] = tp[i];
  }
  const int4 m0 = ((const int4*)mask)[2 * tid];
  const int4 m1 = ((const int4*)mask)[2 * tid + 1];
  const int j3 = (blockIdx.x << 9) + tid;  // phase-3 output index 0..4095
  float y[DD];
#pragma unroll
  for (int k = 0; k < DD; ++k) y[k] = outputs[j3 * DD + k];

  // ---- phase 1: moments over rows 8t..8t+7 (72 floats = 18 float4, exact)
  float acc[55];
#pragma unroll
  for (int k = 0; k < 55; ++k) acc[k] = 0.f;
  {
    const float* f = (const float*)st4;
    const int mk[8] = {m0.x, m0.y, m0.z, m0.w, m1.x, m1.y, m1.z, m1.w};
#pragma unroll
    for (int rr = 0; rr < 8; ++rr) {
      if (mk[rr] != 0) {
        const float* t = f + rr * DD;
        acc[0] += 1.f;
#pragma unroll
        for (int k = 0; k < DD; ++k) acc[1 + k] += t[k];
        int u = 10;
#pragma unroll
        for (int p = 0; p < DD; ++p)
#pragma unroll
          for (int q = p; q < DD; ++q) acc[u++] += t[p] * t[q];
      }
    }
  }
#pragma unroll
  for (int k = 0; k < 55; ++k) {
    float v = acc[k];
#pragma unroll
    for (int off = 32; off > 0; off >>= 1) v += __shfl_down(v, off, 64);
    if ((tid & 63) == 0) part[tid >> 6][k] = v;
  }
  __syncthreads();

  if (tid < 55) {
    double s = 0.0;
#pragma unroll
    for (int w = 0; w < 8; ++w) s += (double)part[w][tid];
    Sd[tid] = s;
  }
  __syncthreads();

  // ---- phase 2: fp64 Gauss-Jordan on wave 0 (lane p owns augmented row p)
  if (tid < 64) {
    const int lane = tid;
    const double cnt = Sd[0];
    const int p = (lane < DD) ? lane : 0;  // junk lanes mirror row 0
    double row[2 * DD];
    {
      const double mu_p = Sd[1 + p] / cnt;
#pragma unroll
      for (int q = 0; q < DD; ++q) {
        const int pp = (p < q) ? p : q;
        const int qq = (p < q) ? q : p;
        const int idx = 10 + 9 * pp - (pp * (pp - 1)) / 2 + (qq - pp);
        row[q] = (Sd[idx] - cnt * mu_p * (Sd[1 + q] / cnt)) / (cnt - 1.0);
        row[DD + q] = (p == q) ? 1.0 : 0.0;
      }
    }
#pragma unroll
    for (int c = 0; c < DD; ++c) {
      const double diag = __shfl(row[c], c, 64);
      const double dinv = 1.0 / diag;
      if (lane == c) {
#pragma unroll
        for (int q = 0; q < 2 * DD; ++q) row[q] *= dinv;
      }
      const double f = (lane == c) ? 0.0 : row[c];
#pragma unroll
      for (int q = 0; q < 2 * DD; ++q) {
        const double pv = __shfl(row[q], c, 64);
        row[q] -= f * pv;
      }
    }
    if (lane < DD) {
#pragma unroll
      for (int q = 0; q < DD; ++q) {
        const float cf = (float)row[DD + q];
        Cs[lane * DD + q] = cf;
        if (blockIdx.x == 0) ws->cinv[lane * DD + q] = cf;
      }
    }
    if (lane == 0 && blockIdx.x == 0) {
      ws->cnt = (float)cnt;
#pragma unroll
      for (int q = 0; q < DD; ++q) ws->mean[q] = (float)(Sd[1 + q] / cnt);
    }
  }
  __syncthreads();

  // ---- phase 3: qy + SoA transpose, ONE output per thread (coalesced)
  {
    const int b = j3 >> 10;
    const int jj = j3 & (NN - 1);
    float C[DD * DD];
#pragma unroll
    for (int k = 0; k < DD * DD; ++k) C[k] = Cs[k];
    float q = 0.f;
#pragma unroll
    for (int p = 0; p < DD; ++p) {
      float s = 0.f;
#pragma unroll
      for (int t = 0; t < DD; ++t) s += C[p * DD + t] * y[t];
      q += y[p] * s;
      ws->yT[(b * DD + p) * NN + jj] = y[p];
    }
    ws->qy[j3] = q;
  }
}

// ---------------------------------------------------------------------------
// Kernel B [R0-verified, fastest measured dist ~9.5us]: one wave per
// row-slot, ONE side per wave, 4 waves/block; no LDS, no __syncthreads, no
// atomics. Lane owns j = c*256 + lane*4 + e => float4 index c*64+lane =>
// 16 B lane stride, fully coalesced. Top-16 = per-lane bitonic sort + 6
// shfl_xor half-cleaner rounds; the re-merge after the LAST round is skipped
// (only the sum of the surviving 16 is needed; half-cleaner output already
// holds exactly the top-16 multiset, bitonically ordered).
// ---------------------------------------------------------------------------
__global__ __launch_bounds__(256) void dist_kernel(
    const float* __restrict__ outputs, const float* __restrict__ targets,
    const int* __restrict__ mask, Ws* __restrict__ ws) {
  const int wv = threadIdx.x >> 6;
  const int lane = threadIdx.x & 63;
  const int s = blockIdx.x * 4 + wv;
  const bool is_intra = (s < NROW);  // wave-uniform
  const int r = s & (NROW - 1);
  const int b = r >> 10;

  if (is_intra && mask[r] == 0) {
    if (lane == 0) ws->rowsum[s] = 0.f;
    return;
  }

  float a[DD];
  if (is_intra) {
#pragma unroll
    for (int k = 0; k < DD; ++k) a[k] = targets[r * DD + k] - ws->mean[k];
  } else {
#pragma unroll
    for (int k = 0; k < DD; ++k) a[k] = outputs[r * DD + k] + ws->mean[k];
  }
  float w[DD];
  float qa = 0.f;
#pragma unroll
  for (int p = 0; p < DD; ++p) {
    float acc = 0.f;
#pragma unroll
    for (int t = 0; t < DD; ++t) acc += ws->cinv[p * DD + t] * a[t];
    w[p] = acc;
    qa += a[p] * acc;
  }

  float v[16];
#pragma unroll
  for (int k = 0; k < 16; ++k) v[k] = 0.f;
  const float* __restrict__ yTb = ws->yT + (size_t)b * DD * NN;
#pragma unroll
  for (int p = 0; p < DD; ++p) {
    const float4* __restrict__ pl = (const float4*)(yTb + (size_t)p * NN);
#pragma unroll
    for (int c = 0; c < 4; ++c) {
      const float4 y4 = pl[c * 64 + lane];
      v[c * 4 + 0] += w[p] * y4.x;
      v[c * 4 + 1] += w[p] * y4.y;
      v[c * 4 + 2] += w[p] * y4.z;
      v[c * 4 + 3] += w[p] * y4.w;
    }
  }
  {
    const float4* __restrict__ q4 = (const float4*)(ws->qy + (size_t)b * NN);
#pragma unroll
    for (int c = 0; c < 4; ++c) {
      const float4 qv = q4[c * 64 + lane];
      v[c * 4 + 0] = qa + qv.x - 2.f * v[c * 4 + 0];
      v[c * 4 + 1] = qa + qv.y - 2.f * v[c * 4 + 1];
      v[c * 4 + 2] = qa + qv.z - 2.f * v[c * 4 + 2];
      v[c * 4 + 3] = qa + qv.w - 2.f * v[c * 4 + 3];
    }
  }

  // per-lane bitonic sort ascending (static indices after unroll)
#pragma unroll
  for (int k = 2; k <= 16; k <<= 1) {
#pragma unroll
    for (int j = k >> 1; j > 0; j >>= 1) {
#pragma unroll
      for (int i = 0; i < 16; ++i) {
        const int l = i ^ j;
        if (l > i) {
          const bool up = ((i & k) == 0);
          const float lo = fminf(v[i], v[l]);
          const float hi = fmaxf(v[i], v[l]);
          v[i] = up ? lo : hi;
          v[l] = up ? hi : lo;
        }
      }
    }
  }

  // 6 cross-lane rounds: half-cleaner min(A[i],B[15-i]) keeps the 16
  // smallest of two ascending 16-lists (bitonic order); re-sort with a
  // 4-stage merge only when another round follows.
#pragma unroll
  for (int off = 1; off < 64; off <<= 1) {
    float pr[16];
#pragma unroll
    for (int i = 0; i < 16; ++i) pr[i] = __shfl_xor(v[i], off, 64);
#pragma unroll
    for (int i = 0; i < 16; ++i) v[i] = fminf(v[i], pr[15 - i]);
    if (off < 32) {
#pragma unroll
      for (int j = 8; j > 0; j >>= 1) {
#pragma unroll
        for (int i = 0; i < 16; ++i) {
          const int l = i ^ j;
          if (l > i) {
            const float lo = fminf(v[i], v[l]);
            const float hi = fmaxf(v[i], v[l]);
            v[i] = lo;
            v[l] = hi;
          }
        }
      }
    }
  }

  float total = v[0];
#pragma unroll
  for (int k = 1; k < 16; ++k) total += v[k];
  if (lane == 0) ws->rowsum[s] = total;
}

// ---------------------------------------------------------------------------
// Kernel C [R0-verified]: one block; reduce 8192 row sums -> three scalars.
// ---------------------------------------------------------------------------
__global__ __launch_bounds__(256) void finalize_kernel(
    const Ws* __restrict__ ws, float* __restrict__ out) {
  const int tid = threadIdx.x;
  double li = 0.0, lo = 0.0;
  for (int k = tid; k < NROW; k += 256) {
    li += (double)ws->rowsum[k];
    lo += (double)ws->rowsum[NROW + k];
  }
#pragma unroll
  for (int off = 32; off > 0; off >>= 1) {
    li += __shfl_down(li, off, 64);
    lo += __shfl_down(lo, off, 64);
  }
  __shared__ double lds_i[4], lds_o[4];
  if ((tid & 63) == 0) {
    lds_i[tid >> 6] = li;
    lds_o[tid >> 6] = lo;
  }
  __syncthreads();
  if (tid == 0) {
    const double si = lds_i[0] + lds_i[1] + lds_i[2] + lds_i[3];
    const double so = lds_o[0] + lds_o[1] + lds_o[2] + lds_o[3];
    const float intra = (float)(si / (double)ws->cnt);
    const float outer = (float)(so / (double)(NROW * KSEL));
    out[0] = intra;
    out[1] = intra;
    out[2] = outer;
  }
}

extern "C" void kernel_launch(void* const* d_in, const int* in_sizes, int n_in,
                              void* d_out, int out_size, void* d_ws,
                              size_t ws_size, hipStream_t stream) {
  const float* outputs = (const float*)d_in[0];  // (4,1024,9) f32
  const float* targets = (const float*)d_in[1];  // (4,1024,9) f32
  const int* mask = (const int*)d_in[2];         // (4,1024) int32
  Ws* ws = (Ws*)d_ws;
  float* out = (float*)d_out;

  prep_kernel<<<8, 512, 0, stream>>>(outputs, targets, mask, ws);
  dist_kernel<<<NBLK, 256, 0, stream>>>(outputs, targets, mask, ws);
  finalize_kernel<<<1, 256, 0, stream>>>(ws, out);
}